// Round 13
// baseline (1626.097 us; speedup 1.0000x reference)
//
#include <hip/hip_runtime.h>
#include <hip/hip_bf16.h>
#include <math.h>

namespace {

constexpr int kS = 1020, kD = 1024, kTPB = 17, kDH = 64;
constexpr int kVOBS = 4096, kVACT = 16;
constexpr int kBS = 4080;          // B*S
constexpr float kEPS = 1e-3f;

typedef float f32x4 __attribute__((ext_vector_type(4)));
typedef __bf16 bfx8 __attribute__((ext_vector_type(8)));
typedef unsigned short u16;
typedef u16 us8 __attribute__((ext_vector_type(8)));
typedef u16 us4 __attribute__((ext_vector_type(4)));

__device__ __forceinline__ float bf2f(u16 u) {
  union { unsigned int i; float f; } v; v.i = (unsigned int)u << 16; return v.f;
}
__device__ __forceinline__ u16 f2bf(float f) {
  union { float f; unsigned int i; } v; v.f = f;
  unsigned int r = v.i + 0x7FFFu + ((v.i >> 16) & 1u);
  return (u16)(r >> 16);
}

// ---------- embed
__global__ void k_embed(const int* __restrict__ tokens, const float* __restrict__ pos_emb,
                        const float* __restrict__ emb_obs, const float* __restrict__ emb_act,
                        float* __restrict__ x) {
  int bs = blockIdx.x;
  int s = bs % kS;
  int tk = tokens[bs];
  bool obs = (s % kTPB) < (kTPB - 1);
  const float* e;
  if (obs) { int t2 = tk < kVOBS - 1 ? tk : kVOBS - 1; e = emb_obs + (size_t)t2 * kD; }
  else     { int t2 = tk < kVACT - 1 ? tk : kVACT - 1; e = emb_act + (size_t)t2 * kD; }
  int c = threadIdx.x * 4;
  float4 ev = *(const float4*)(e + c);
  float4 pv = *(const float4*)(pos_emb + (size_t)s * kD + c);
  float4 o; o.x = ev.x + pv.x; o.y = ev.y + pv.y; o.z = ev.z + pv.z; o.w = ev.w + pv.w;
  *(float4*)(x + (size_t)bs * kD + c) = o;
}

// ---------- bias pack (QKV)
__global__ void k_pack_bias(const float* __restrict__ bq, const float* __restrict__ bk,
                            const float* __restrict__ bv, float* __restrict__ bqkv) {
  int idx = blockIdx.x * 256 + threadIdx.x;      // 0..12287
  int l = idx / 3072, rem = idx % 3072;
  int sel = rem >> 10, cc = rem & 1023;
  const float* src = sel == 0 ? bq : (sel == 1 ? bk : bv);
  bqkv[idx] = src[l * kD + cc];
}

// ---------- LayerNorm: f32 in -> bf16 out.
__global__ void k_ln(const float* __restrict__ x, const float* __restrict__ g,
                     const float* __restrict__ b, u16* __restrict__ out) {
  int row = blockIdx.x;
  int t = threadIdx.x;
  const float* xr = x + (size_t)row * kD;
  float4 v = *(const float4*)(xr + t * 4);
  float s1 = v.x + v.y + v.z + v.w;
  float s2 = v.x * v.x + v.y * v.y + v.z * v.z + v.w * v.w;
  #pragma unroll
  for (int m = 32; m; m >>= 1) { s1 += __shfl_xor(s1, m); s2 += __shfl_xor(s2, m); }
  __shared__ float ls1[4], ls2[4];
  int w = t >> 6;
  if ((t & 63) == 0) { ls1[w] = s1; ls2[w] = s2; }
  __syncthreads();
  float S1 = ls1[0] + ls1[1] + ls1[2] + ls1[3];
  float S2 = ls2[0] + ls2[1] + ls2[2] + ls2[3];
  float mean = S1 * (1.0f / kD);
  float var = S2 * (1.0f / kD) - mean * mean;
  float rs = rsqrtf(var + kEPS);
  int c = t * 4;
  float4 gv = *(const float4*)(g + c);
  float4 bv = *(const float4*)(b + c);
  us4 o;
  o[0] = f2bf((v.x - mean) * rs * gv.x + bv.x);
  o[1] = f2bf((v.y - mean) * rs * gv.y + bv.y);
  o[2] = f2bf((v.z - mean) * rs * gv.z + bv.z);
  o[3] = f2bf((v.w - mean) * rs * gv.w + bv.w);
  *(us4*)(out + (size_t)row * kD + c) = o;
}

// ---------- transpose + f32->bf16 (single)
__global__ void k_transpose(const float* __restrict__ in, u16* __restrict__ out,
                            int R, int C, int ld) {
  __shared__ float tile[32][33];
  int tx = threadIdx.x, ty = threadIdx.y;
  int c0 = blockIdx.x * 32, r0 = blockIdx.y * 32;
  #pragma unroll
  for (int i = 0; i < 4; ++i)
    tile[ty + i * 8][tx] = in[(size_t)(r0 + ty + i * 8) * ld + c0 + tx];
  __syncthreads();
  #pragma unroll
  for (int i = 0; i < 4; ++i)
    out[(size_t)(c0 + ty + i * 8) * R + r0 + tx] = f2bf(tile[tx][ty + i * 8]);
}

// ---------- batched 1024x1024 transpose (4 segments via blockIdx.z)
struct T4 {
  const float* in0; const float* in1; const float* in2; const float* in3;
  u16* out0; u16* out1; u16* out2; u16* out3;
  int ld;
};
__global__ void k_transpose4(T4 sp) {
  const float* in; u16* out;
  switch (blockIdx.z) {
    case 0:  in = sp.in0; out = sp.out0; break;
    case 1:  in = sp.in1; out = sp.out1; break;
    case 2:  in = sp.in2; out = sp.out2; break;
    default: in = sp.in3; out = sp.out3; break;
  }
  __shared__ float tile[32][33];
  int tx = threadIdx.x, ty = threadIdx.y;
  int c0 = blockIdx.x * 32, r0 = blockIdx.y * 32;
  #pragma unroll
  for (int i = 0; i < 4; ++i)
    tile[ty + i * 8][tx] = in[(size_t)(r0 + ty + i * 8) * sp.ld + c0 + tx];
  __syncthreads();
  #pragma unroll
  for (int i = 0; i < 4; ++i)
    out[(size_t)(c0 + ty + i * 8) * 1024 + r0 + tx] = f2bf(tile[tx][ty + i * 8]);
}

// ---------- V transpose: qkv V-section [s][d] -> vt [bh][d=64][s=1020] (bf16)
__global__ void k_vtrans(const u16* __restrict__ qkv, u16* __restrict__ vt) {
  __shared__ u16 tile[32][33];
  int bh = blockIdx.z; int b = bh >> 4, hh = bh & 15;
  int s0 = blockIdx.x * 32, d0 = blockIdx.y * 32;
  int tx = threadIdx.x, ty = threadIdx.y;
  const u16* src = qkv + ((size_t)(b * kS)) * 3072 + 2048 + hh * 64;
  #pragma unroll
  for (int i = 0; i < 4; ++i) {
    int s = s0 + ty + i * 8;
    tile[ty + i * 8][tx] = (s < kS) ? src[(size_t)s * 3072 + d0 + tx] : (u16)0;
  }
  __syncthreads();
  if (s0 + tx < kS) {
    #pragma unroll
    for (int i = 0; i < 4; ++i)
      vt[((size_t)bh * 64 + d0 + ty + i * 8) * kS + s0 + tx] = tile[tx][ty + i * 8];
  }
}

// ---------- 256x256 8-phase GEMM (T2+T3+T4+T5 template). N multiple of 256.
// EPI: 0 bf16, 2 bf16 gelu, 3 f32 resid+=val (out holds resid), 4 f32 store.
template <int EPI>
__global__ void __launch_bounds__(512, 2)
k_gemm256(const u16* __restrict__ A, const u16* __restrict__ Bt, const float* __restrict__ bias,
          void* __restrict__ out, int M, int K, int ldo) {
  __shared__ alignas(16) u16 As[2][256 * 64];
  __shared__ alignas(16) u16 Bs[2][256 * 64];
  const int tid = threadIdx.x;
  const int lane = tid & 63, wv = tid >> 6;
  const int wm = wv >> 2, wn = wv & 3;              // 2 x 4 waves
  const int m0 = blockIdx.x * 256, n0 = blockIdx.y * 256;
  f32x4 acc[8][4] = {};

  auto stageIter = [&](int buf, int k0, int it) {
    int u = (it & 3) * 512 + tid;                   // 0..2047
    int row = u >> 3, g = u & 7;
    int gsw = g ^ (row & 7);
    int grow;
    const u16* srcBase;
    u16* dstBase;
    if (it < 4) {
      grow = m0 + row; if (grow >= M) grow = M - 1;
      srcBase = A; dstBase = &As[buf][0];
    } else {
      grow = n0 + row;
      srcBase = Bt; dstBase = &Bs[buf][0];
    }
    const u16* src = srcBase + (size_t)grow * K + k0 + gsw * 8;
    u16* dst = dstBase + ((it & 3) * 512 + wv * 64) * 8;
    __builtin_amdgcn_global_load_lds(
        (const __attribute__((address_space(1))) unsigned int*)src,
        (__attribute__((address_space(3))) unsigned int*)dst, 16, 0, 0);
  };

  const int nt = K >> 6;
  #pragma unroll
  for (int it = 0; it < 8; ++it) stageIter(0, 0, it);

  for (int t = 0; t < nt; ++t) {
    const int pb = t & 1;
    const int k0n = (t + 1) << 6;
    const bool pf = (t + 1 < nt);
    asm volatile("s_waitcnt vmcnt(0)" ::: "memory");
    __builtin_amdgcn_s_barrier();
    __builtin_amdgcn_sched_barrier(0);

    #pragma unroll
    for (int kh = 0; kh < 2; ++kh) {
      bfx8 bfr[4], afr[4];
      #pragma unroll
      for (int n = 0; n < 4; ++n) {
        int row = wn * 64 + n * 16 + (lane & 15);
        bfr[n] = *(const bfx8*)(&Bs[pb][row * 64 + ((((kh << 2) + (lane >> 4)) ^ (row & 7)) << 3)]);
      }
      #pragma unroll
      for (int j = 0; j < 4; ++j) {
        int row = wm * 128 + j * 16 + (lane & 15);
        afr[j] = *(const bfx8*)(&As[pb][row * 64 + ((((kh << 2) + (lane >> 4)) ^ (row & 7)) << 3)]);
      }
      if (pf) { stageIter(pb ^ 1, k0n, kh * 4 + 0); stageIter(pb ^ 1, k0n, kh * 4 + 1); }
      __builtin_amdgcn_s_barrier();
      asm volatile("s_waitcnt lgkmcnt(0)" ::: "memory");
      __builtin_amdgcn_sched_barrier(0);
      __builtin_amdgcn_s_setprio(1);
      #pragma unroll
      for (int j = 0; j < 4; ++j)
        #pragma unroll
        for (int n = 0; n < 4; ++n)
          acc[j][n] = __builtin_amdgcn_mfma_f32_16x16x32_bf16(afr[j], bfr[n], acc[j][n], 0, 0, 0);
      __builtin_amdgcn_s_setprio(0);
      __builtin_amdgcn_s_barrier();

      #pragma unroll
      for (int j = 0; j < 4; ++j) {
        int row = wm * 128 + 64 + j * 16 + (lane & 15);
        afr[j] = *(const bfx8*)(&As[pb][row * 64 + ((((kh << 2) + (lane >> 4)) ^ (row & 7)) << 3)]);
      }
      if (pf) { stageIter(pb ^ 1, k0n, kh * 4 + 2); stageIter(pb ^ 1, k0n, kh * 4 + 3); }
      __builtin_amdgcn_s_barrier();
      asm volatile("s_waitcnt lgkmcnt(0)" ::: "memory");
      __builtin_amdgcn_sched_barrier(0);
      __builtin_amdgcn_s_setprio(1);
      #pragma unroll
      for (int j = 0; j < 4; ++j)
        #pragma unroll
        for (int n = 0; n < 4; ++n)
          acc[4 + j][n] = __builtin_amdgcn_mfma_f32_16x16x32_bf16(afr[j], bfr[n], acc[4 + j][n], 0, 0, 0);
      __builtin_amdgcn_s_setprio(0);
      __builtin_amdgcn_s_barrier();
    }
  }

  #pragma unroll
  for (int jf = 0; jf < 8; ++jf) {
    #pragma unroll
    for (int n = 0; n < 4; ++n) {
      int gcol = n0 + wn * 64 + n * 16 + (lane & 15);
      float bv = bias ? bias[gcol] : 0.0f;
      #pragma unroll
      for (int r = 0; r < 4; ++r) {
        int grow = m0 + wm * 128 + jf * 16 + (lane >> 4) * 4 + r;
        if (grow >= M) continue;
        float val = acc[jf][n][r] + bv;
        size_t o2 = (size_t)grow * ldo + gcol;
        if (EPI == 0) {
          ((u16*)out)[o2] = f2bf(val);
        } else if (EPI == 2) {
          ((u16*)out)[o2] = f2bf(0.5f * val * (1.f + erff(val * 0.70710678118654752440f)));
        } else if (EPI == 3) {
          ((float*)out)[o2] = ((float*)out)[o2] + val;   // out holds residual
        } else {
          ((float*)out)[o2] = val;
        }
      }
    }
  }
}

// ---------- MFMA GEMM (N=1024 shapes): 3-buffer counted-vmcnt, BM x 128.
// (round-11 proven kernel) EPI: 1 bf16 relu, 3 f32 resid+val.
template <int EPI, int BM>
__global__ void __launch_bounds__(256)
k_gemm(const u16* __restrict__ A, const u16* __restrict__ Bt, const float* __restrict__ bias,
       const float* __restrict__ resid, void* __restrict__ out, int M, int N, int K, int ldo) {
  constexpr int MFRAG = BM / 32;
  constexpr int LOADS = BM / 64 + 2;
  __shared__ alignas(16) u16 As[3][BM * 32];
  __shared__ alignas(16) u16 Bs[3][128 * 32];
  int tid = threadIdx.x;
  int m0 = blockIdx.x * BM, n0 = blockIdx.y * 128;
  int lane = tid & 63, wv = tid >> 6;
  int wm = wv >> 1, wn = wv & 1;
  f32x4 acc[MFRAG][4] = {};

  auto stage = [&](int buf, int k0) {
    #pragma unroll
    for (int n = 0; n < BM / 64; ++n) {
      int u = n * 256 + tid;
      int r = u >> 2, ch = u & 3;
      int gr = m0 + r; if (gr >= M) gr = M - 1;
      int cg = ch ^ ((r >> 1) & 3);
      const u16* src = A + (size_t)gr * K + k0 + cg * 8;
      __builtin_amdgcn_global_load_lds(
          (const __attribute__((address_space(1))) unsigned int*)src,
          (__attribute__((address_space(3))) unsigned int*)&As[buf][(n * 256 + wv * 64) * 8],
          16, 0, 0);
    }
    #pragma unroll
    for (int n = 0; n < 2; ++n) {
      int u = n * 256 + tid;
      int r = u >> 2, ch = u & 3;
      int cg = ch ^ ((r >> 1) & 3);
      const u16* src = Bt + (size_t)(n0 + r) * K + k0 + cg * 8;
      __builtin_amdgcn_global_load_lds(
          (const __attribute__((address_space(1))) unsigned int*)src,
          (__attribute__((address_space(3))) unsigned int*)&Bs[buf][(n * 256 + wv * 64) * 8],
          16, 0, 0);
    }
  };

  const int nk = K >> 5;
  stage(0, 0);
  stage(1, 32);
  stage(2, 64);
  for (int t = 0; t < nk; ++t) {
    int cur = t % 3;
    if (t + 2 < nk)
      asm volatile("s_waitcnt vmcnt(%0)" :: "i"(2 * LOADS) : "memory");
    else if (t + 1 < nk)
      asm volatile("s_waitcnt vmcnt(%0)" :: "i"(LOADS) : "memory");
    else
      asm volatile("s_waitcnt vmcnt(0)" ::: "memory");
    __builtin_amdgcn_s_barrier();
    __builtin_amdgcn_sched_barrier(0);

    bfx8 af[MFRAG], bfr[4];
    int ch = lane >> 4;
    #pragma unroll
    for (int mf = 0; mf < MFRAG; ++mf) {
      int row = wm * (BM / 2) + mf * 16 + (lane & 15);
      af[mf] = *(const bfx8*)(&As[cur][row * 32 + ((ch ^ ((row >> 1) & 3)) << 3)]);
    }
    #pragma unroll
    for (int nf = 0; nf < 4; ++nf) {
      int row = wn * 64 + nf * 16 + (lane & 15);
      bfr[nf] = *(const bfx8*)(&Bs[cur][row * 32 + ((ch ^ ((row >> 1) & 3)) << 3)]);
    }
    asm volatile("s_waitcnt lgkmcnt(0)" ::: "memory");
    __builtin_amdgcn_s_barrier();
    __builtin_amdgcn_sched_barrier(0);
    if (t + 3 < nk) stage(cur, (t + 3) << 5);

    #pragma unroll
    for (int mf = 0; mf < MFRAG; ++mf)
      #pragma unroll
      for (int nf = 0; nf < 4; ++nf)
        acc[mf][nf] = __builtin_amdgcn_mfma_f32_16x16x32_bf16(af[mf], bfr[nf], acc[mf][nf], 0, 0, 0);
  }

  #pragma unroll
  for (int mf = 0; mf < MFRAG; ++mf) {
    #pragma unroll
    for (int nf = 0; nf < 4; ++nf) {
      int gcol = n0 + wn * 64 + nf * 16 + (lane & 15);
      float bv = bias ? bias[gcol] : 0.0f;
      #pragma unroll
      for (int r = 0; r < 4; ++r) {
        int grow = m0 + wm * (BM / 2) + mf * 16 + (lane >> 4) * 4 + r;
        if (grow >= M) continue;
        float val = acc[mf][nf][r] + bv;
        size_t off2 = (size_t)grow * ldo + gcol;
        if (EPI == 1) {
          ((u16*)out)[off2] = f2bf(val > 0.f ? val : 0.f);
        } else {
          ((float*)out)[off2] = resid[off2] + val;
        }
      }
    }
  }
}

// ---------- MFMA flash attention (swapped-operand). Q/K from qkv (stride ldin);
// V from pre-transposed vt [bh][64][kS]. Longest blocks launch first.
__device__ __forceinline__ int swz(int row, int colu16) {
  return (row * 64 + colu16) ^ ((row & 7) << 3) ^ ((row & 24) << 1);
}

__global__ void __launch_bounds__(256)
k_attn(const u16* __restrict__ q, const u16* __restrict__ k, const u16* __restrict__ vt,
       u16* __restrict__ o, int ldin) {
  __shared__ u16 Kl[64 * 64];
  __shared__ u16 Vt[64 * 64];
  const int qbi = gridDim.x - 1 - blockIdx.x;   // reversed: long blocks first
  const int qb = qbi * 64;
  const int bh = blockIdx.y;
  const int b = bh >> 4, hh = bh & 15;
  const int tid = threadIdx.x;
  const int lane = tid & 63, w = tid >> 6;
  const int g = lane >> 4, c = lane & 15;
  const int q0 = qb + w * 16;
  const size_t base = (size_t)(b * kS) * ldin + hh * kDH;

  bfx8 qf0, qf1;
  {
    int qr = q0 + c; if (qr >= kS) qr = kS - 1;
    const u16* qp = q + base + (size_t)qr * ldin + g * 8;
    qf0 = *(const bfx8*)(qp);
    qf1 = *(const bfx8*)(qp + 32);
  }

  float mst = -1e30f, lsum = 0.f;
  f32x4 ot[4] = {};

  const int ntiles = qbi + 1;
  for (int t = 0; t < ntiles; ++t) {
    const int kt = t * 64;
    {
      int kr = tid >> 2, ds2 = (tid & 3) * 16;
      int kg = kt + kr; if (kg >= kS) kg = kS - 1;
      const u16* kp = k + base + (size_t)kg * ldin + ds2;
      us8 a0 = *(const us8*)(kp);
      us8 a1 = *(const us8*)(kp + 8);
      *(us8*)(&Kl[swz(kr, ds2)]) = a0;
      *(us8*)(&Kl[swz(kr, ds2 + 8)]) = a1;
      const u16* vrow = vt + ((size_t)bh * 64 + kr) * kS;
      if (kt + 64 <= kS) {
        #pragma unroll
        for (int j = 0; j < 4; ++j) {
          us4 v4 = *(const us4*)(vrow + kt + ds2 + 4 * j);
          *(us4*)(&Vt[swz(kr, ds2 + 4 * j)]) = v4;
        }
      } else {
        #pragma unroll
        for (int j = 0; j < 16; ++j) {
          int cc = kt + ds2 + j; if (cc > kS - 1) cc = kS - 1;
          Vt[swz(kr, ds2 + j)] = vrow[cc];
        }
      }
    }
    __syncthreads();

    f32x4 s[4];
    #pragma unroll
    for (int kb = 0; kb < 4; ++kb) {
      bfx8 kf0 = *(const bfx8*)(&Kl[swz(kb * 16 + c, g * 8)]);
      bfx8 kf1 = *(const bfx8*)(&Kl[swz(kb * 16 + c, g * 8 + 32)]);
      f32x4 acc = {};
      acc = __builtin_amdgcn_mfma_f32_16x16x32_bf16(kf0, qf0, acc, 0, 0, 0);
      acc = __builtin_amdgcn_mfma_f32_16x16x32_bf16(kf1, qf1, acc, 0, 0, 0);
      s[kb] = acc;
    }

    const int qg = q0 + c;
    const bool diag = (kt + 63 > q0);
    float p[4][4];
    float tmax = -1e30f;
    #pragma unroll
    for (int kb = 0; kb < 4; ++kb)
      #pragma unroll
      for (int r = 0; r < 4; ++r) {
        float val = s[kb][r] * 0.125f;
        if (diag && (kt + kb * 16 + g * 4 + r > qg)) val = -1e30f;
        p[kb][r] = val;
        tmax = fmaxf(tmax, val);
      }
    tmax = fmaxf(tmax, __shfl_xor(tmax, 16));
    tmax = fmaxf(tmax, __shfl_xor(tmax, 32));
    float mnew = fmaxf(mst, tmax);
    float alpha = __expf(mst - mnew);
    float psum = 0.f;
    #pragma unroll
    for (int kb = 0; kb < 4; ++kb)
      #pragma unroll
      for (int r = 0; r < 4; ++r) {
        float e = __expf(p[kb][r] - mnew);
        p[kb][r] = e;
        psum += e;
      }
    psum += __shfl_xor(psum, 16);
    psum += __shfl_xor(psum, 32);
    lsum = lsum * alpha + psum;
    mst = mnew;
    #pragma unroll
    for (int db = 0; db < 4; ++db) {
      ot[db][0] *= alpha; ot[db][1] *= alpha;
      ot[db][2] *= alpha; ot[db][3] *= alpha;
    }

    #pragma unroll
    for (int h = 0; h < 2; ++h) {
      bfx8 pf;
      #pragma unroll
      for (int j = 0; j < 8; ++j)
        pf[j] = (__bf16)p[2 * h + (j >> 2)][j & 3];
      #pragma unroll
      for (int db = 0; db < 4; ++db) {
        us4 lo = *(const us4*)(&Vt[swz(16 * db + c, 32 * h + 4 * g)]);
        us4 hi = *(const us4*)(&Vt[swz(16 * db + c, 32 * h + 16 + 4 * g)]);
        union { us8 u; bfx8 bf; } cv;
        cv.u[0] = lo[0]; cv.u[1] = lo[1]; cv.u[2] = lo[2]; cv.u[3] = lo[3];
        cv.u[4] = hi[0]; cv.u[5] = hi[1]; cv.u[6] = hi[2]; cv.u[7] = hi[3];
        ot[db] = __builtin_amdgcn_mfma_f32_16x16x32_bf16(cv.bf, pf, ot[db], 0, 0, 0);
      }
    }
    __syncthreads();
  }

  if (q0 + c < kS) {
    float inv = 1.0f / lsum;
    u16* op = o + (size_t)(b * kS) * kD + hh * kDH + (size_t)(q0 + c) * kD;
    #pragma unroll
    for (int db = 0; db < 4; ++db)
      #pragma unroll
      for (int r = 0; r < 4; ++r)
        op[16 * db + 4 * g + r] = f2bf(ot[db][r] * inv);
  }
}

// ---------- gathers
__global__ void k_gather_obs(const u16* __restrict__ xf, u16* __restrict__ xo) {
  int r = blockIdx.x;
  int b = r / 960, rr = r % 960;
  int j = rr & 15, blk = rr >> 4;
  int s = blk * kTPB + j + (j == 15 ? 1 : 0);
  const unsigned int* src = (const unsigned int*)(xf + ((size_t)(b * kS + s)) * kD);
  unsigned int* dst = (unsigned int*)(xo + (size_t)r * kD);
  dst[threadIdx.x] = src[threadIdx.x];
  dst[threadIdx.x + 256] = src[threadIdx.x + 256];
}
__global__ void k_gather_act(const u16* __restrict__ xf, u16* __restrict__ xe) {
  int r = blockIdx.x;
  int b = r / 60, rr = r % 60;
  int s = rr * kTPB + (kTPB - 1);
  const unsigned int* src = (const unsigned int*)(xf + ((size_t)(b * kS + s)) * kD);
  unsigned int* dst = (unsigned int*)(xe + (size_t)r * kD);
  dst[threadIdx.x] = src[threadIdx.x];
  dst[threadIdx.x + 256] = src[threadIdx.x + 256];
}

// ---------- ends head (f32 out)
__global__ void k_ends(const u16* __restrict__ t2, const float* __restrict__ he2,
                       const float* __restrict__ be2, float* __restrict__ out) {
  int r = blockIdx.x;
  int t = threadIdx.x;
  float p0 = 0.f, p1 = 0.f;
  for (int j = t; j < kD; j += 256) {
    float xv = bf2f(t2[(size_t)r * kD + j]);
    p0 += xv * he2[j * 2];
    p1 += xv * he2[j * 2 + 1];
  }
  #pragma unroll
  for (int msk = 32; msk; msk >>= 1) { p0 += __shfl_xor(p0, msk); p1 += __shfl_xor(p1, msk); }
  __shared__ float l0[4], l1[4];
  int w = t >> 6;
  if ((t & 63) == 0) { l0[w] = p0; l1[w] = p1; }
  __syncthreads();
  if (t == 0) {
    out[r * 2 + 0] = l0[0] + l0[1] + l0[2] + l0[3] + be2[0];
    out[r * 2 + 1] = l1[0] + l1[1] + l1[2] + l1[3] + be2[1];
  }
}

} // namespace

extern "C" void kernel_launch(void* const* d_in, const int* in_sizes, int n_in,
                              void* d_out, int out_size, void* d_ws, size_t ws_size,
                              hipStream_t stream) {
  const int*   tokens  = (const int*)  d_in[0];
  const float* pos_emb = (const float*)d_in[1];
  const float* emb_obs = (const float*)d_in[2];
  const float* emb_act = (const float*)d_in[3];
  const float* ln1_g = (const float*)d_in[4];
  const float* ln1_b = (const float*)d_in[5];
  const float* wq = (const float*)d_in[6];
  const float* bq = (const float*)d_in[7];
  const float* wk = (const float*)d_in[8];
  const float* bk = (const float*)d_in[9];
  const float* wv = (const float*)d_in[10];
  const float* bv = (const float*)d_in[11];
  const float* wo = (const float*)d_in[12];
  const float* bo = (const float*)d_in[13];
  const float* ln2_g = (const float*)d_in[14];
  const float* ln2_b = (const float*)d_in[15];
  const float* w1 = (const float*)d_in[16];
  const float* b1 = (const float*)d_in[17];
  const float* w2 = (const float*)d_in[18];
  const float* b2 = (const float*)d_in[19];
  const float* lnf_g = (const float*)d_in[20];
  const float* lnf_b = (const float*)d_in[21];
  const float* ho1 = (const float*)d_in[22];
  const float* bo1 = (const float*)d_in[23];
  const float* ho2 = (const float*)d_in[24];
  const float* bo2 = (const float*)d_in[25];
  const float* he1 = (const float*)d_in[26];
  const float* be1 = (const float*)d_in[27];
  const float* he2 = (const float*)d_in[28];
  const float* be2 = (const float*)d_in[29];
  (void)in_sizes; (void)n_in; (void)out_size; (void)ws_size;

  // ---- workspace: ~74.9 MB (vt reuses h)
  char* ws = (char*)d_ws;
  size_t off = 0;
  auto alloc = [&](size_t bytes) -> char* {
    char* p = ws + off; off += (bytes + 255) & ~(size_t)255; return p;
  };
  u16*   wTbig = (u16*)alloc((size_t)4096 * 1024 * 2);    // 8 MB stacked B^T
  u16*   w2T   = (u16*)alloc((size_t)1024 * 4096 * 2);    // 8 MB w2^T / he1^T
  float* x  = (float*)alloc((size_t)kBS * kD * 4);        // 16.71 MB residual
  u16*   h  = (u16*)alloc((size_t)kBS * kD * 2);          // 8.36 MB LN out / vt
  char*  scr = alloc((size_t)kBS * 4096 * 2);             // 33.42 MB
  float* bqkv = (float*)alloc((size_t)4 * 3072 * 4);      // 48 KB packed QKV bias
  const size_t slotB = (size_t)kBS * kD * 2;
  u16* qkv = (u16*)scr;                               // [4080][3072]
  u16* ob  = (u16*)(scr + (size_t)kBS * 3072 * 2);    // [4080][1024]
  u16* mid = (u16*)scr;                               // [4080][4096]
  u16* vt  = h;                                       // [64][64][1020]
  u16* xf = (u16*)scr;
  u16* xo = (u16*)(scr + slotB);
  u16* t1 = (u16*)(scr + 2 * slotB);
  u16* xe = (u16*)(scr + 3 * slotB);
  u16* t2 = (u16*)(scr + 3 * slotB + (size_t)240 * kD * 2 + 256);

  dim3 tb(32, 8);
  dim3 tg(32, 32);
  k_embed<<<kBS, 256, 0, stream>>>(tokens, pos_emb, emb_obs, emb_act, x);
  k_pack_bias<<<48, 256, 0, stream>>>(bq, bk, bv, bqkv);

  const size_t MB1 = (size_t)1024 * 1024;
  for (int i = 0; i < 4; ++i) {
    const size_t wOff = (size_t)i * kD * kD;
    k_ln<<<kBS, 256, 0, stream>>>(x, ln1_g + i * kD, ln1_b + i * kD, h);

    {
      T4 sp{wq + wOff, wk + wOff, wv + wOff, wo + wOff,
            wTbig, wTbig + MB1, wTbig + 2 * MB1, wTbig + 3 * MB1, 1024};
      k_transpose4<<<dim3(32, 32, 4), tb, 0, stream>>>(sp);
    }
    k_gemm256<0><<<dim3(16, 12), 512, 0, stream>>>(h, wTbig, bqkv + i * 3072, qkv,
                                                   kBS, 1024, 3072);

    k_vtrans<<<dim3(32, 2, 64), tb, 0, stream>>>(qkv, vt);   // h dead -> vt
    k_attn<<<dim3(16, 64), 256, 0, stream>>>(qkv, qkv + 1024, vt, ob, 3072);

    k_gemm<3, 64><<<dim3(64, 8), 256, 0, stream>>>(ob, wTbig + 3 * MB1, bo + i * kD, x, x,
                                                   kBS, 1024, 1024, 1024);

    k_ln<<<kBS, 256, 0, stream>>>(x, ln2_g + i * kD, ln2_b + i * kD, h);

    {
      const float* w1b = w1 + (size_t)i * kD * 4096;
      T4 sp{w1b, w1b + 1024, w1b + 2048, w1b + 3072,
            wTbig, wTbig + MB1, wTbig + 2 * MB1, wTbig + 3 * MB1, 4096};
      k_transpose4<<<dim3(32, 32, 4), tb, 0, stream>>>(sp);
    }
    k_transpose<<<dim3(32, 128), tb, 0, stream>>>(w2 + (size_t)i * 4096 * kD, w2T,
                                                  4096, 1024, 1024);
    k_gemm256<2><<<dim3(16, 16), 512, 0, stream>>>(h, wTbig, b1 + (size_t)i * 4096,
                                                   mid, kBS, 1024, 4096);
    // FFN2 on the 256-wide template: x += mid @ w2 + b2 (64 blocks, per-CU work
    // equal to FFN1's -> predicted ~FFN1 duration)
    k_gemm256<3><<<dim3(16, 4), 512, 0, stream>>>(mid, w2T, b2 + i * kD, x,
                                                  kBS, 4096, 1024);
  }

  k_ln<<<kBS, 256, 0, stream>>>(x, lnf_g, lnf_b, xf);
  k_gather_obs<<<3840, 256, 0, stream>>>(xf, xo);
  k_gather_act<<<240, 256, 0, stream>>>(xf, xe);

  // obs head
  k_transpose<<<tg, tb, 0, stream>>>(ho1, wTbig, 1024, 1024, 1024);
  k_gemm<1, 64><<<dim3(60, 8), 256, 0, stream>>>(xo, wTbig, bo1, nullptr, t1,
                                                 3840, 1024, 1024, 1024);
  k_transpose<<<tg, tb, 0, stream>>>(he1, w2T, 1024, 1024, 1024);
  {
    T4 sp{ho2, ho2 + 1024, ho2 + 2048, ho2 + 3072,
          wTbig, wTbig + MB1, wTbig + 2 * MB1, wTbig + 3 * MB1, 4096};
    k_transpose4<<<dim3(32, 32, 4), tb, 0, stream>>>(sp);
  }
  k_gemm256<4><<<dim3(15, 16), 512, 0, stream>>>(t1, wTbig, bo2,
                                                 (float*)d_out, 3840, 1024, 4096);
  // ends head
  k_gemm<1, 64><<<dim3(4, 8), 256, 0, stream>>>(xe, w2T, be1, nullptr, t2,
                                                240, 1024, 1024, 1024);
  k_ends<<<240, 256, 0, stream>>>(t2, he2, be2, (float*)d_out + (size_t)3840 * 4096);
}

// Round 14
// 1382.000 us; speedup vs baseline: 1.1766x; 1.1766x over previous
//
#include <hip/hip_runtime.h>
#include <hip/hip_bf16.h>
#include <math.h>

namespace {

constexpr int kS = 1020, kD = 1024, kTPB = 17, kDH = 64;
constexpr int kVOBS = 4096, kVACT = 16;
constexpr int kBS = 4080;          // B*S
constexpr float kEPS = 1e-3f;

typedef float f32x4 __attribute__((ext_vector_type(4)));
typedef __bf16 bfx8 __attribute__((ext_vector_type(8)));
typedef unsigned short u16;
typedef u16 us8 __attribute__((ext_vector_type(8)));
typedef u16 us4 __attribute__((ext_vector_type(4)));

__device__ __forceinline__ float bf2f(u16 u) {
  union { unsigned int i; float f; } v; v.i = (unsigned int)u << 16; return v.f;
}
__device__ __forceinline__ u16 f2bf(float f) {
  union { float f; unsigned int i; } v; v.f = f;
  unsigned int r = v.i + 0x7FFFu + ((v.i >> 16) & 1u);
  return (u16)(r >> 16);
}

// ---------- embed
__global__ void k_embed(const int* __restrict__ tokens, const float* __restrict__ pos_emb,
                        const float* __restrict__ emb_obs, const float* __restrict__ emb_act,
                        float* __restrict__ x) {
  int bs = blockIdx.x;
  int s = bs % kS;
  int tk = tokens[bs];
  bool obs = (s % kTPB) < (kTPB - 1);
  const float* e;
  if (obs) { int t2 = tk < kVOBS - 1 ? tk : kVOBS - 1; e = emb_obs + (size_t)t2 * kD; }
  else     { int t2 = tk < kVACT - 1 ? tk : kVACT - 1; e = emb_act + (size_t)t2 * kD; }
  int c = threadIdx.x * 4;
  float4 ev = *(const float4*)(e + c);
  float4 pv = *(const float4*)(pos_emb + (size_t)s * kD + c);
  float4 o; o.x = ev.x + pv.x; o.y = ev.y + pv.y; o.z = ev.z + pv.z; o.w = ev.w + pv.w;
  *(float4*)(x + (size_t)bs * kD + c) = o;
}

// ---------- bias pack (QKV)
__global__ void k_pack_bias(const float* __restrict__ bq, const float* __restrict__ bk,
                            const float* __restrict__ bv, float* __restrict__ bqkv) {
  int idx = blockIdx.x * 256 + threadIdx.x;      // 0..12287
  int l = idx / 3072, rem = idx % 3072;
  int sel = rem >> 10, cc = rem & 1023;
  const float* src = sel == 0 ? bq : (sel == 1 ? bk : bv);
  bqkv[idx] = src[l * kD + cc];
}

// ---------- LayerNorm: f32 in -> bf16 out.
__global__ void k_ln(const float* __restrict__ x, const float* __restrict__ g,
                     const float* __restrict__ b, u16* __restrict__ out) {
  int row = blockIdx.x;
  int t = threadIdx.x;
  const float* xr = x + (size_t)row * kD;
  float4 v = *(const float4*)(xr + t * 4);
  float s1 = v.x + v.y + v.z + v.w;
  float s2 = v.x * v.x + v.y * v.y + v.z * v.z + v.w * v.w;
  #pragma unroll
  for (int m = 32; m; m >>= 1) { s1 += __shfl_xor(s1, m); s2 += __shfl_xor(s2, m); }
  __shared__ float ls1[4], ls2[4];
  int w = t >> 6;
  if ((t & 63) == 0) { ls1[w] = s1; ls2[w] = s2; }
  __syncthreads();
  float S1 = ls1[0] + ls1[1] + ls1[2] + ls1[3];
  float S2 = ls2[0] + ls2[1] + ls2[2] + ls2[3];
  float mean = S1 * (1.0f / kD);
  float var = S2 * (1.0f / kD) - mean * mean;
  float rs = rsqrtf(var + kEPS);
  int c = t * 4;
  float4 gv = *(const float4*)(g + c);
  float4 bv = *(const float4*)(b + c);
  us4 o;
  o[0] = f2bf((v.x - mean) * rs * gv.x + bv.x);
  o[1] = f2bf((v.y - mean) * rs * gv.y + bv.y);
  o[2] = f2bf((v.z - mean) * rs * gv.z + bv.z);
  o[3] = f2bf((v.w - mean) * rs * gv.w + bv.w);
  *(us4*)(out + (size_t)row * kD + c) = o;
}

// ---------- transpose + f32->bf16 (single)
__global__ void k_transpose(const float* __restrict__ in, u16* __restrict__ out,
                            int R, int C, int ld) {
  __shared__ float tile[32][33];
  int tx = threadIdx.x, ty = threadIdx.y;
  int c0 = blockIdx.x * 32, r0 = blockIdx.y * 32;
  #pragma unroll
  for (int i = 0; i < 4; ++i)
    tile[ty + i * 8][tx] = in[(size_t)(r0 + ty + i * 8) * ld + c0 + tx];
  __syncthreads();
  #pragma unroll
  for (int i = 0; i < 4; ++i)
    out[(size_t)(c0 + ty + i * 8) * R + r0 + tx] = f2bf(tile[tx][ty + i * 8]);
}

// ---------- batched 1024x1024 transpose (4 segments via blockIdx.z)
struct T4 {
  const float* in0; const float* in1; const float* in2; const float* in3;
  u16* out0; u16* out1; u16* out2; u16* out3;
  int ld;
};
__global__ void k_transpose4(T4 sp) {
  const float* in; u16* out;
  switch (blockIdx.z) {
    case 0:  in = sp.in0; out = sp.out0; break;
    case 1:  in = sp.in1; out = sp.out1; break;
    case 2:  in = sp.in2; out = sp.out2; break;
    default: in = sp.in3; out = sp.out3; break;
  }
  __shared__ float tile[32][33];
  int tx = threadIdx.x, ty = threadIdx.y;
  int c0 = blockIdx.x * 32, r0 = blockIdx.y * 32;
  #pragma unroll
  for (int i = 0; i < 4; ++i)
    tile[ty + i * 8][tx] = in[(size_t)(r0 + ty + i * 8) * sp.ld + c0 + tx];
  __syncthreads();
  #pragma unroll
  for (int i = 0; i < 4; ++i)
    out[(size_t)(c0 + ty + i * 8) * 1024 + r0 + tx] = f2bf(tile[tx][ty + i * 8]);
}

// ---------- V transpose: qkv V-section [s][d] -> vt [bh][d=64][s=1020] (bf16)
__global__ void k_vtrans(const u16* __restrict__ qkv, u16* __restrict__ vt) {
  __shared__ u16 tile[32][33];
  int bh = blockIdx.z; int b = bh >> 4, hh = bh & 15;
  int s0 = blockIdx.x * 32, d0 = blockIdx.y * 32;
  int tx = threadIdx.x, ty = threadIdx.y;
  const u16* src = qkv + ((size_t)(b * kS)) * 3072 + 2048 + hh * 64;
  #pragma unroll
  for (int i = 0; i < 4; ++i) {
    int s = s0 + ty + i * 8;
    tile[ty + i * 8][tx] = (s < kS) ? src[(size_t)s * 3072 + d0 + tx] : (u16)0;
  }
  __syncthreads();
  if (s0 + tx < kS) {
    #pragma unroll
    for (int i = 0; i < 4; ++i)
      vt[((size_t)bh * 64 + d0 + ty + i * 8) * kS + s0 + tx] = tile[tx][ty + i * 8];
  }
}

// ---------- 256x256 8-phase GEMM (T2+T3+T4+T5 template). N multiple of 256.
// EPI: 0 bf16, 2 bf16 gelu, 4 f32 store.
template <int EPI>
__global__ void __launch_bounds__(512, 2)
k_gemm256(const u16* __restrict__ A, const u16* __restrict__ Bt, const float* __restrict__ bias,
          void* __restrict__ out, int M, int K, int ldo) {
  __shared__ alignas(16) u16 As[2][256 * 64];
  __shared__ alignas(16) u16 Bs[2][256 * 64];
  const int tid = threadIdx.x;
  const int lane = tid & 63, wv = tid >> 6;
  const int wm = wv >> 2, wn = wv & 3;              // 2 x 4 waves
  const int m0 = blockIdx.x * 256, n0 = blockIdx.y * 256;
  f32x4 acc[8][4] = {};

  auto stageIter = [&](int buf, int k0, int it) {
    int u = (it & 3) * 512 + tid;                   // 0..2047
    int row = u >> 3, g = u & 7;
    int gsw = g ^ (row & 7);
    int grow;
    const u16* srcBase;
    u16* dstBase;
    if (it < 4) {
      grow = m0 + row; if (grow >= M) grow = M - 1;
      srcBase = A; dstBase = &As[buf][0];
    } else {
      grow = n0 + row;
      srcBase = Bt; dstBase = &Bs[buf][0];
    }
    const u16* src = srcBase + (size_t)grow * K + k0 + gsw * 8;
    u16* dst = dstBase + ((it & 3) * 512 + wv * 64) * 8;
    __builtin_amdgcn_global_load_lds(
        (const __attribute__((address_space(1))) unsigned int*)src,
        (__attribute__((address_space(3))) unsigned int*)dst, 16, 0, 0);
  };

  const int nt = K >> 6;
  #pragma unroll
  for (int it = 0; it < 8; ++it) stageIter(0, 0, it);

  for (int t = 0; t < nt; ++t) {
    const int pb = t & 1;
    const int k0n = (t + 1) << 6;
    const bool pf = (t + 1 < nt);
    asm volatile("s_waitcnt vmcnt(0)" ::: "memory");
    __builtin_amdgcn_s_barrier();
    __builtin_amdgcn_sched_barrier(0);

    #pragma unroll
    for (int kh = 0; kh < 2; ++kh) {
      bfx8 bfr[4], afr[4];
      #pragma unroll
      for (int n = 0; n < 4; ++n) {
        int row = wn * 64 + n * 16 + (lane & 15);
        bfr[n] = *(const bfx8*)(&Bs[pb][row * 64 + ((((kh << 2) + (lane >> 4)) ^ (row & 7)) << 3)]);
      }
      #pragma unroll
      for (int j = 0; j < 4; ++j) {
        int row = wm * 128 + j * 16 + (lane & 15);
        afr[j] = *(const bfx8*)(&As[pb][row * 64 + ((((kh << 2) + (lane >> 4)) ^ (row & 7)) << 3)]);
      }
      if (pf) { stageIter(pb ^ 1, k0n, kh * 4 + 0); stageIter(pb ^ 1, k0n, kh * 4 + 1); }
      __builtin_amdgcn_s_barrier();
      asm volatile("s_waitcnt lgkmcnt(0)" ::: "memory");
      __builtin_amdgcn_sched_barrier(0);
      __builtin_amdgcn_s_setprio(1);
      #pragma unroll
      for (int j = 0; j < 4; ++j)
        #pragma unroll
        for (int n = 0; n < 4; ++n)
          acc[j][n] = __builtin_amdgcn_mfma_f32_16x16x32_bf16(afr[j], bfr[n], acc[j][n], 0, 0, 0);
      __builtin_amdgcn_s_setprio(0);
      __builtin_amdgcn_s_barrier();

      #pragma unroll
      for (int j = 0; j < 4; ++j) {
        int row = wm * 128 + 64 + j * 16 + (lane & 15);
        afr[j] = *(const bfx8*)(&As[pb][row * 64 + ((((kh << 2) + (lane >> 4)) ^ (row & 7)) << 3)]);
      }
      if (pf) { stageIter(pb ^ 1, k0n, kh * 4 + 2); stageIter(pb ^ 1, k0n, kh * 4 + 3); }
      __builtin_amdgcn_s_barrier();
      asm volatile("s_waitcnt lgkmcnt(0)" ::: "memory");
      __builtin_amdgcn_sched_barrier(0);
      __builtin_amdgcn_s_setprio(1);
      #pragma unroll
      for (int j = 0; j < 4; ++j)
        #pragma unroll
        for (int n = 0; n < 4; ++n)
          acc[4 + j][n] = __builtin_amdgcn_mfma_f32_16x16x32_bf16(afr[j], bfr[n], acc[4 + j][n], 0, 0, 0);
      __builtin_amdgcn_s_setprio(0);
      __builtin_amdgcn_s_barrier();
    }
  }

  #pragma unroll
  for (int jf = 0; jf < 8; ++jf) {
    #pragma unroll
    for (int n = 0; n < 4; ++n) {
      int gcol = n0 + wn * 64 + n * 16 + (lane & 15);
      float bv = bias ? bias[gcol] : 0.0f;
      #pragma unroll
      for (int r = 0; r < 4; ++r) {
        int grow = m0 + wm * 128 + jf * 16 + (lane >> 4) * 4 + r;
        if (grow >= M) continue;
        float val = acc[jf][n][r] + bv;
        size_t o2 = (size_t)grow * ldo + gcol;
        if (EPI == 0) {
          ((u16*)out)[o2] = f2bf(val);
        } else if (EPI == 2) {
          ((u16*)out)[o2] = f2bf(0.5f * val * (1.f + erff(val * 0.70710678118654752440f)));
        } else {
          ((float*)out)[o2] = val;
        }
      }
    }
  }
}

// ---------- split-K 256x256 GEMM for FFN2 (K=4096, N=1024).
// grid (M/256, 4, 3). z=0: K[0:1344), epilogue x += val + bias.
// z=1: K[1344:2688) -> P1 (bf16). z=2: K[2688:4096) -> P2 (bf16).
// Deterministic (disjoint outputs, no atomics). Reduce via k_addp.
__global__ void __launch_bounds__(512, 2)
k_gemm256sk(const u16* __restrict__ A, const u16* __restrict__ Bt, const float* __restrict__ bias,
            float* __restrict__ xout, u16* __restrict__ P1, u16* __restrict__ P2,
            int M, int Ktot, int ldo) {
  __shared__ alignas(16) u16 As[2][256 * 64];
  __shared__ alignas(16) u16 Bs[2][256 * 64];
  const int tid = threadIdx.x;
  const int lane = tid & 63, wv = tid >> 6;
  const int wm = wv >> 2, wn = wv & 3;
  const int m0 = blockIdx.x * 256, n0 = blockIdx.y * 256;
  const int z = blockIdx.z;
  const int kStart = z * 1344;
  const int nt = (z == 2) ? 22 : 21;               // 1344,1344,1408 (x64)
  f32x4 acc[8][4] = {};

  auto stageIter = [&](int buf, int k0, int it) {
    int u = (it & 3) * 512 + tid;
    int row = u >> 3, g = u & 7;
    int gsw = g ^ (row & 7);
    int grow;
    const u16* srcBase;
    u16* dstBase;
    if (it < 4) {
      grow = m0 + row; if (grow >= M) grow = M - 1;
      srcBase = A; dstBase = &As[buf][0];
    } else {
      grow = n0 + row;
      srcBase = Bt; dstBase = &Bs[buf][0];
    }
    const u16* src = srcBase + (size_t)grow * Ktot + k0 + gsw * 8;
    u16* dst = dstBase + ((it & 3) * 512 + wv * 64) * 8;
    __builtin_amdgcn_global_load_lds(
        (const __attribute__((address_space(1))) unsigned int*)src,
        (__attribute__((address_space(3))) unsigned int*)dst, 16, 0, 0);
  };

  #pragma unroll
  for (int it = 0; it < 8; ++it) stageIter(0, kStart, it);

  for (int t = 0; t < nt; ++t) {
    const int pb = t & 1;
    const int k0n = kStart + ((t + 1) << 6);
    const bool pf = (t + 1 < nt);
    asm volatile("s_waitcnt vmcnt(0)" ::: "memory");
    __builtin_amdgcn_s_barrier();
    __builtin_amdgcn_sched_barrier(0);

    #pragma unroll
    for (int kh = 0; kh < 2; ++kh) {
      bfx8 bfr[4], afr[4];
      #pragma unroll
      for (int n = 0; n < 4; ++n) {
        int row = wn * 64 + n * 16 + (lane & 15);
        bfr[n] = *(const bfx8*)(&Bs[pb][row * 64 + ((((kh << 2) + (lane >> 4)) ^ (row & 7)) << 3)]);
      }
      #pragma unroll
      for (int j = 0; j < 4; ++j) {
        int row = wm * 128 + j * 16 + (lane & 15);
        afr[j] = *(const bfx8*)(&As[pb][row * 64 + ((((kh << 2) + (lane >> 4)) ^ (row & 7)) << 3)]);
      }
      if (pf) { stageIter(pb ^ 1, k0n, kh * 4 + 0); stageIter(pb ^ 1, k0n, kh * 4 + 1); }
      __builtin_amdgcn_s_barrier();
      asm volatile("s_waitcnt lgkmcnt(0)" ::: "memory");
      __builtin_amdgcn_sched_barrier(0);
      __builtin_amdgcn_s_setprio(1);
      #pragma unroll
      for (int j = 0; j < 4; ++j)
        #pragma unroll
        for (int n = 0; n < 4; ++n)
          acc[j][n] = __builtin_amdgcn_mfma_f32_16x16x32_bf16(afr[j], bfr[n], acc[j][n], 0, 0, 0);
      __builtin_amdgcn_s_setprio(0);
      __builtin_amdgcn_s_barrier();

      #pragma unroll
      for (int j = 0; j < 4; ++j) {
        int row = wm * 128 + 64 + j * 16 + (lane & 15);
        afr[j] = *(const bfx8*)(&As[pb][row * 64 + ((((kh << 2) + (lane >> 4)) ^ (row & 7)) << 3)]);
      }
      if (pf) { stageIter(pb ^ 1, k0n, kh * 4 + 2); stageIter(pb ^ 1, k0n, kh * 4 + 3); }
      __builtin_amdgcn_s_barrier();
      asm volatile("s_waitcnt lgkmcnt(0)" ::: "memory");
      __builtin_amdgcn_sched_barrier(0);
      __builtin_amdgcn_s_setprio(1);
      #pragma unroll
      for (int j = 0; j < 4; ++j)
        #pragma unroll
        for (int n = 0; n < 4; ++n)
          acc[4 + j][n] = __builtin_amdgcn_mfma_f32_16x16x32_bf16(afr[j], bfr[n], acc[4 + j][n], 0, 0, 0);
      __builtin_amdgcn_s_setprio(0);
      __builtin_amdgcn_s_barrier();
    }
  }

  u16* P = (z == 1) ? P1 : P2;
  #pragma unroll
  for (int jf = 0; jf < 8; ++jf) {
    #pragma unroll
    for (int n = 0; n < 4; ++n) {
      int gcol = n0 + wn * 64 + n * 16 + (lane & 15);
      float bv = bias[gcol];
      #pragma unroll
      for (int r = 0; r < 4; ++r) {
        int grow = m0 + wm * 128 + jf * 16 + (lane >> 4) * 4 + r;
        if (grow >= M) continue;
        size_t o2 = (size_t)grow * ldo + gcol;
        if (z == 0) {
          xout[o2] += acc[jf][n][r] + bv;
        } else {
          P[o2] = f2bf(acc[jf][n][r]);
        }
      }
    }
  }
}

// ---------- reduce: x += P1 + P2 over kBS*kD elements (4/thread)
__global__ void k_addp(float* __restrict__ x, const u16* __restrict__ P1,
                       const u16* __restrict__ P2) {
  int i = (blockIdx.x * 256 + threadIdx.x) * 4;
  float4 xv = *(float4*)(x + i);
  us4 a = *(const us4*)(P1 + i);
  us4 b = *(const us4*)(P2 + i);
  xv.x += bf2f(a[0]) + bf2f(b[0]);
  xv.y += bf2f(a[1]) + bf2f(b[1]);
  xv.z += bf2f(a[2]) + bf2f(b[2]);
  xv.w += bf2f(a[3]) + bf2f(b[3]);
  *(float4*)(x + i) = xv;
}

// ---------- MFMA GEMM (N=1024 shapes): 3-buffer counted-vmcnt, BM x 128.
// EPI: 1 bf16 relu, 3 f32 resid+val.
template <int EPI, int BM>
__global__ void __launch_bounds__(256)
k_gemm(const u16* __restrict__ A, const u16* __restrict__ Bt, const float* __restrict__ bias,
       const float* __restrict__ resid, void* __restrict__ out, int M, int N, int K, int ldo) {
  constexpr int MFRAG = BM / 32;
  constexpr int LOADS = BM / 64 + 2;
  __shared__ alignas(16) u16 As[3][BM * 32];
  __shared__ alignas(16) u16 Bs[3][128 * 32];
  int tid = threadIdx.x;
  int m0 = blockIdx.x * BM, n0 = blockIdx.y * 128;
  int lane = tid & 63, wv = tid >> 6;
  int wm = wv >> 1, wn = wv & 1;
  f32x4 acc[MFRAG][4] = {};

  auto stage = [&](int buf, int k0) {
    #pragma unroll
    for (int n = 0; n < BM / 64; ++n) {
      int u = n * 256 + tid;
      int r = u >> 2, ch = u & 3;
      int gr = m0 + r; if (gr >= M) gr = M - 1;
      int cg = ch ^ ((r >> 1) & 3);
      const u16* src = A + (size_t)gr * K + k0 + cg * 8;
      __builtin_amdgcn_global_load_lds(
          (const __attribute__((address_space(1))) unsigned int*)src,
          (__attribute__((address_space(3))) unsigned int*)&As[buf][(n * 256 + wv * 64) * 8],
          16, 0, 0);
    }
    #pragma unroll
    for (int n = 0; n < 2; ++n) {
      int u = n * 256 + tid;
      int r = u >> 2, ch = u & 3;
      int cg = ch ^ ((r >> 1) & 3);
      const u16* src = Bt + (size_t)(n0 + r) * K + k0 + cg * 8;
      __builtin_amdgcn_global_load_lds(
          (const __attribute__((address_space(1))) unsigned int*)src,
          (__attribute__((address_space(3))) unsigned int*)&Bs[buf][(n * 256 + wv * 64) * 8],
          16, 0, 0);
    }
  };

  const int nk = K >> 5;
  stage(0, 0);
  stage(1, 32);
  stage(2, 64);
  for (int t = 0; t < nk; ++t) {
    int cur = t % 3;
    if (t + 2 < nk)
      asm volatile("s_waitcnt vmcnt(%0)" :: "i"(2 * LOADS) : "memory");
    else if (t + 1 < nk)
      asm volatile("s_waitcnt vmcnt(%0)" :: "i"(LOADS) : "memory");
    else
      asm volatile("s_waitcnt vmcnt(0)" ::: "memory");
    __builtin_amdgcn_s_barrier();
    __builtin_amdgcn_sched_barrier(0);

    bfx8 af[MFRAG], bfr[4];
    int ch = lane >> 4;
    #pragma unroll
    for (int mf = 0; mf < MFRAG; ++mf) {
      int row = wm * (BM / 2) + mf * 16 + (lane & 15);
      af[mf] = *(const bfx8*)(&As[cur][row * 32 + ((ch ^ ((row >> 1) & 3)) << 3)]);
    }
    #pragma unroll
    for (int nf = 0; nf < 4; ++nf) {
      int row = wn * 64 + nf * 16 + (lane & 15);
      bfr[nf] = *(const bfx8*)(&Bs[cur][row * 32 + ((ch ^ ((row >> 1) & 3)) << 3)]);
    }
    asm volatile("s_waitcnt lgkmcnt(0)" ::: "memory");
    __builtin_amdgcn_s_barrier();
    __builtin_amdgcn_sched_barrier(0);
    if (t + 3 < nk) stage(cur, (t + 3) << 5);

    #pragma unroll
    for (int mf = 0; mf < MFRAG; ++mf)
      #pragma unroll
      for (int nf = 0; nf < 4; ++nf)
        acc[mf][nf] = __builtin_amdgcn_mfma_f32_16x16x32_bf16(af[mf], bfr[nf], acc[mf][nf], 0, 0, 0);
  }

  #pragma unroll
  for (int mf = 0; mf < MFRAG; ++mf) {
    #pragma unroll
    for (int nf = 0; nf < 4; ++nf) {
      int gcol = n0 + wn * 64 + nf * 16 + (lane & 15);
      float bv = bias ? bias[gcol] : 0.0f;
      #pragma unroll
      for (int r = 0; r < 4; ++r) {
        int grow = m0 + wm * (BM / 2) + mf * 16 + (lane >> 4) * 4 + r;
        if (grow >= M) continue;
        float val = acc[mf][nf][r] + bv;
        size_t off2 = (size_t)grow * ldo + gcol;
        if (EPI == 1) {
          ((u16*)out)[off2] = f2bf(val > 0.f ? val : 0.f);
        } else {
          ((float*)out)[off2] = resid[off2] + val;
        }
      }
    }
  }
}

// ---------- MFMA flash attention (swapped-operand). Q/K from qkv (stride ldin);
// V from pre-transposed vt [bh][64][kS]. Longest blocks launch first.
__device__ __forceinline__ int swz(int row, int colu16) {
  return (row * 64 + colu16) ^ ((row & 7) << 3) ^ ((row & 24) << 1);
}

__global__ void __launch_bounds__(256)
k_attn(const u16* __restrict__ q, const u16* __restrict__ k, const u16* __restrict__ vt,
       u16* __restrict__ o, int ldin) {
  __shared__ u16 Kl[64 * 64];
  __shared__ u16 Vt[64 * 64];
  const int qbi = gridDim.x - 1 - blockIdx.x;   // reversed: long blocks first
  const int qb = qbi * 64;
  const int bh = blockIdx.y;
  const int b = bh >> 4, hh = bh & 15;
  const int tid = threadIdx.x;
  const int lane = tid & 63, w = tid >> 6;
  const int g = lane >> 4, c = lane & 15;
  const int q0 = qb + w * 16;
  const size_t base = (size_t)(b * kS) * ldin + hh * kDH;

  bfx8 qf0, qf1;
  {
    int qr = q0 + c; if (qr >= kS) qr = kS - 1;
    const u16* qp = q + base + (size_t)qr * ldin + g * 8;
    qf0 = *(const bfx8*)(qp);
    qf1 = *(const bfx8*)(qp + 32);
  }

  float mst = -1e30f, lsum = 0.f;
  f32x4 ot[4] = {};

  const int ntiles = qbi + 1;
  for (int t = 0; t < ntiles; ++t) {
    const int kt = t * 64;
    {
      int kr = tid >> 2, ds2 = (tid & 3) * 16;
      int kg = kt + kr; if (kg >= kS) kg = kS - 1;
      const u16* kp = k + base + (size_t)kg * ldin + ds2;
      us8 a0 = *(const us8*)(kp);
      us8 a1 = *(const us8*)(kp + 8);
      *(us8*)(&Kl[swz(kr, ds2)]) = a0;
      *(us8*)(&Kl[swz(kr, ds2 + 8)]) = a1;
      const u16* vrow = vt + ((size_t)bh * 64 + kr) * kS;
      if (kt + 64 <= kS) {
        #pragma unroll
        for (int j = 0; j < 4; ++j) {
          us4 v4 = *(const us4*)(vrow + kt + ds2 + 4 * j);
          *(us4*)(&Vt[swz(kr, ds2 + 4 * j)]) = v4;
        }
      } else {
        #pragma unroll
        for (int j = 0; j < 16; ++j) {
          int cc = kt + ds2 + j; if (cc > kS - 1) cc = kS - 1;
          Vt[swz(kr, ds2 + j)] = vrow[cc];
        }
      }
    }
    __syncthreads();

    f32x4 s[4];
    #pragma unroll
    for (int kb = 0; kb < 4; ++kb) {
      bfx8 kf0 = *(const bfx8*)(&Kl[swz(kb * 16 + c, g * 8)]);
      bfx8 kf1 = *(const bfx8*)(&Kl[swz(kb * 16 + c, g * 8 + 32)]);
      f32x4 acc = {};
      acc = __builtin_amdgcn_mfma_f32_16x16x32_bf16(kf0, qf0, acc, 0, 0, 0);
      acc = __builtin_amdgcn_mfma_f32_16x16x32_bf16(kf1, qf1, acc, 0, 0, 0);
      s[kb] = acc;
    }

    const int qg = q0 + c;
    const bool diag = (kt + 63 > q0);
    float p[4][4];
    float tmax = -1e30f;
    #pragma unroll
    for (int kb = 0; kb < 4; ++kb)
      #pragma unroll
      for (int r = 0; r < 4; ++r) {
        float val = s[kb][r] * 0.125f;
        if (diag && (kt + kb * 16 + g * 4 + r > qg)) val = -1e30f;
        p[kb][r] = val;
        tmax = fmaxf(tmax, val);
      }
    tmax = fmaxf(tmax, __shfl_xor(tmax, 16));
    tmax = fmaxf(tmax, __shfl_xor(tmax, 32));
    float mnew = fmaxf(mst, tmax);
    float alpha = __expf(mst - mnew);
    float psum = 0.f;
    #pragma unroll
    for (int kb = 0; kb < 4; ++kb)
      #pragma unroll
      for (int r = 0; r < 4; ++r) {
        float e = __expf(p[kb][r] - mnew);
        p[kb][r] = e;
        psum += e;
      }
    psum += __shfl_xor(psum, 16);
    psum += __shfl_xor(psum, 32);
    lsum = lsum * alpha + psum;
    mst = mnew;
    #pragma unroll
    for (int db = 0; db < 4; ++db) {
      ot[db][0] *= alpha; ot[db][1] *= alpha;
      ot[db][2] *= alpha; ot[db][3] *= alpha;
    }

    #pragma unroll
    for (int h = 0; h < 2; ++h) {
      bfx8 pf;
      #pragma unroll
      for (int j = 0; j < 8; ++j)
        pf[j] = (__bf16)p[2 * h + (j >> 2)][j & 3];
      #pragma unroll
      for (int db = 0; db < 4; ++db) {
        us4 lo = *(const us4*)(&Vt[swz(16 * db + c, 32 * h + 4 * g)]);
        us4 hi = *(const us4*)(&Vt[swz(16 * db + c, 32 * h + 16 + 4 * g)]);
        union { us8 u; bfx8 bf; } cv;
        cv.u[0] = lo[0]; cv.u[1] = lo[1]; cv.u[2] = lo[2]; cv.u[3] = lo[3];
        cv.u[4] = hi[0]; cv.u[5] = hi[1]; cv.u[6] = hi[2]; cv.u[7] = hi[3];
        ot[db] = __builtin_amdgcn_mfma_f32_16x16x32_bf16(cv.bf, pf, ot[db], 0, 0, 0);
      }
    }
    __syncthreads();
  }

  if (q0 + c < kS) {
    float inv = 1.0f / lsum;
    u16* op = o + (size_t)(b * kS) * kD + hh * kDH + (size_t)(q0 + c) * kD;
    #pragma unroll
    for (int db = 0; db < 4; ++db)
      #pragma unroll
      for (int r = 0; r < 4; ++r)
        op[16 * db + 4 * g + r] = f2bf(ot[db][r] * inv);
  }
}

// ---------- gathers
__global__ void k_gather_obs(const u16* __restrict__ xf, u16* __restrict__ xo) {
  int r = blockIdx.x;
  int b = r / 960, rr = r % 960;
  int j = rr & 15, blk = rr >> 4;
  int s = blk * kTPB + j + (j == 15 ? 1 : 0);
  const unsigned int* src = (const unsigned int*)(xf + ((size_t)(b * kS + s)) * kD);
  unsigned int* dst = (unsigned int*)(xo + (size_t)r * kD);
  dst[threadIdx.x] = src[threadIdx.x];
  dst[threadIdx.x + 256] = src[threadIdx.x + 256];
}
__global__ void k_gather_act(const u16* __restrict__ xf, u16* __restrict__ xe) {
  int r = blockIdx.x;
  int b = r / 60, rr = r % 60;
  int s = rr * kTPB + (kTPB - 1);
  const unsigned int* src = (const unsigned int*)(xf + ((size_t)(b * kS + s)) * kD);
  unsigned int* dst = (unsigned int*)(xe + (size_t)r * kD);
  dst[threadIdx.x] = src[threadIdx.x];
  dst[threadIdx.x + 256] = src[threadIdx.x + 256];
}

// ---------- ends head (f32 out)
__global__ void k_ends(const u16* __restrict__ t2, const float* __restrict__ he2,
                       const float* __restrict__ be2, float* __restrict__ out) {
  int r = blockIdx.x;
  int t = threadIdx.x;
  float p0 = 0.f, p1 = 0.f;
  for (int j = t; j < kD; j += 256) {
    float xv = bf2f(t2[(size_t)r * kD + j]);
    p0 += xv * he2[j * 2];
    p1 += xv * he2[j * 2 + 1];
  }
  #pragma unroll
  for (int msk = 32; msk; msk >>= 1) { p0 += __shfl_xor(p0, msk); p1 += __shfl_xor(p1, msk); }
  __shared__ float l0[4], l1[4];
  int w = t >> 6;
  if ((t & 63) == 0) { l0[w] = p0; l1[w] = p1; }
  __syncthreads();
  if (t == 0) {
    out[r * 2 + 0] = l0[0] + l0[1] + l0[2] + l0[3] + be2[0];
    out[r * 2 + 1] = l1[0] + l1[1] + l1[2] + l1[3] + be2[1];
  }
}

} // namespace

extern "C" void kernel_launch(void* const* d_in, const int* in_sizes, int n_in,
                              void* d_out, int out_size, void* d_ws, size_t ws_size,
                              hipStream_t stream) {
  const int*   tokens  = (const int*)  d_in[0];
  const float* pos_emb = (const float*)d_in[1];
  const float* emb_obs = (const float*)d_in[2];
  const float* emb_act = (const float*)d_in[3];
  const float* ln1_g = (const float*)d_in[4];
  const float* ln1_b = (const float*)d_in[5];
  const float* wq = (const float*)d_in[6];
  const float* bq = (const float*)d_in[7];
  const float* wk = (const float*)d_in[8];
  const float* bk = (const float*)d_in[9];
  const float* wv = (const float*)d_in[10];
  const float* bv = (const float*)d_in[11];
  const float* wo = (const float*)d_in[12];
  const float* bo = (const float*)d_in[13];
  const float* ln2_g = (const float*)d_in[14];
  const float* ln2_b = (const float*)d_in[15];
  const float* w1 = (const float*)d_in[16];
  const float* b1 = (const float*)d_in[17];
  const float* w2 = (const float*)d_in[18];
  const float* b2 = (const float*)d_in[19];
  const float* lnf_g = (const float*)d_in[20];
  const float* lnf_b = (const float*)d_in[21];
  const float* ho1 = (const float*)d_in[22];
  const float* bo1 = (const float*)d_in[23];
  const float* ho2 = (const float*)d_in[24];
  const float* bo2 = (const float*)d_in[25];
  const float* he1 = (const float*)d_in[26];
  const float* be1 = (const float*)d_in[27];
  const float* he2 = (const float*)d_in[28];
  const float* be2 = (const float*)d_in[29];
  (void)in_sizes; (void)n_in; (void)out_size; (void)ws_size;

  // ---- workspace: ~74.9 MB (vt reuses h; split-K partials reuse h & wTbig)
  char* ws = (char*)d_ws;
  size_t off = 0;
  auto alloc = [&](size_t bytes) -> char* {
    char* p = ws + off; off += (bytes + 255) & ~(size_t)255; return p;
  };
  u16*   wTbig = (u16*)alloc((size_t)4096 * 1024 * 2);    // 8 MB stacked B^T / P2
  u16*   w2T   = (u16*)alloc((size_t)1024 * 4096 * 2);    // 8 MB w2^T / he1^T
  float* x  = (float*)alloc((size_t)kBS * kD * 4);        // 16.71 MB residual
  u16*   h  = (u16*)alloc((size_t)kBS * kD * 2);          // 8.36 MB LN out / vt / P1
  char*  scr = alloc((size_t)kBS * 4096 * 2);             // 33.42 MB
  float* bqkv = (float*)alloc((size_t)4 * 3072 * 4);      // 48 KB packed QKV bias
  const size_t slotB = (size_t)kBS * kD * 2;
  u16* qkv = (u16*)scr;                               // [4080][3072]
  u16* ob  = (u16*)(scr + (size_t)kBS * 3072 * 2);    // [4080][1024]
  u16* mid = (u16*)scr;                               // [4080][4096]
  u16* vt  = h;                                       // [64][64][1020]
  u16* xf = (u16*)scr;
  u16* xo = (u16*)(scr + slotB);
  u16* t1 = (u16*)(scr + 2 * slotB);
  u16* xe = (u16*)(scr + 3 * slotB);
  u16* t2 = (u16*)(scr + 3 * slotB + (size_t)240 * kD * 2 + 256);

  dim3 tb(32, 8);
  dim3 tg(32, 32);
  k_embed<<<kBS, 256, 0, stream>>>(tokens, pos_emb, emb_obs, emb_act, x);
  k_pack_bias<<<48, 256, 0, stream>>>(bq, bk, bv, bqkv);

  const size_t MB1 = (size_t)1024 * 1024;
  for (int i = 0; i < 4; ++i) {
    const size_t wOff = (size_t)i * kD * kD;
    k_ln<<<kBS, 256, 0, stream>>>(x, ln1_g + i * kD, ln1_b + i * kD, h);

    {
      T4 sp{wq + wOff, wk + wOff, wv + wOff, wo + wOff,
            wTbig, wTbig + MB1, wTbig + 2 * MB1, wTbig + 3 * MB1, 1024};
      k_transpose4<<<dim3(32, 32, 4), tb, 0, stream>>>(sp);
    }
    k_gemm256<0><<<dim3(16, 12), 512, 0, stream>>>(h, wTbig, bqkv + i * 3072, qkv,
                                                   kBS, 1024, 3072);

    k_vtrans<<<dim3(32, 2, 64), tb, 0, stream>>>(qkv, vt);   // h dead -> vt
    k_attn<<<dim3(16, 64), 256, 0, stream>>>(qkv, qkv + 1024, vt, ob, 3072);

    k_gemm<3, 64><<<dim3(64, 8), 256, 0, stream>>>(ob, wTbig + 3 * MB1, bo + i * kD, x, x,
                                                   kBS, 1024, 1024, 1024);

    k_ln<<<kBS, 256, 0, stream>>>(x, ln2_g + i * kD, ln2_b + i * kD, h);

    {
      const float* w1b = w1 + (size_t)i * kD * 4096;
      T4 sp{w1b, w1b + 1024, w1b + 2048, w1b + 3072,
            wTbig, wTbig + MB1, wTbig + 2 * MB1, wTbig + 3 * MB1, 4096};
      k_transpose4<<<dim3(32, 32, 4), tb, 0, stream>>>(sp);
    }
    k_transpose<<<dim3(32, 128), tb, 0, stream>>>(w2 + (size_t)i * 4096 * kD, w2T,
                                                  4096, 1024, 1024);
    k_gemm256<2><<<dim3(16, 16), 512, 0, stream>>>(h, wTbig, b1 + (size_t)i * 4096,
                                                   mid, kBS, 1024, 4096);
    // FFN2 split-K=3: z0 -> x += val+b2 (K 0:1344); z1 -> P1=h; z2 -> P2=wTbig.
    // h (LN2 out) and wTbig (w1T) are both dead after FFN1.
    k_gemm256sk<<<dim3(16, 4, 3), 512, 0, stream>>>(mid, w2T, b2 + i * kD, x,
                                                    h, wTbig, kBS, 4096, 1024);
    k_addp<<<kBS, 256, 0, stream>>>(x, h, wTbig);
  }

  k_ln<<<kBS, 256, 0, stream>>>(x, lnf_g, lnf_b, xf);
  k_gather_obs<<<3840, 256, 0, stream>>>(xf, xo);
  k_gather_act<<<240, 256, 0, stream>>>(xf, xe);

  // obs head
  k_transpose<<<tg, tb, 0, stream>>>(ho1, wTbig, 1024, 1024, 1024);
  k_gemm<1, 64><<<dim3(60, 8), 256, 0, stream>>>(xo, wTbig, bo1, nullptr, t1,
                                                 3840, 1024, 1024, 1024);
  k_transpose<<<tg, tb, 0, stream>>>(he1, w2T, 1024, 1024, 1024);
  {
    T4 sp{ho2, ho2 + 1024, ho2 + 2048, ho2 + 3072,
          wTbig, wTbig + MB1, wTbig + 2 * MB1, wTbig + 3 * MB1, 4096};
    k_transpose4<<<dim3(32, 32, 4), tb, 0, stream>>>(sp);
  }
  k_gemm256<4><<<dim3(15, 16), 512, 0, stream>>>(t1, wTbig, bo2,
                                                 (float*)d_out, 3840, 1024, 4096);
  // ends head
  k_gemm<1, 64><<<dim3(4, 8), 256, 0, stream>>>(xe, w2T, be1, nullptr, t2,
                                                240, 1024, 1024, 1024);
  k_ends<<<240, 256, 0, stream>>>(t2, he2, be2, (float*)d_out + (size_t)3840 * 4096);
}